// Round 1
// baseline (3763.665 us; speedup 1.0000x reference)
//
#include <hip/hip_runtime.h>
#include <math.h>

namespace {

constexpr int T = 4096;
constexpr int B = 256;
constexpr int I = 64;
constexpr int H = 256;
constexpr int O = 64;

constexpr int RED_S  = 260;  // 256 + 4 pad (260 % 32 == 4 -> spreads banks)
constexpr int RED2_S = 66;   // 64 + 2 pad

// 512 threads/block, one block per batch row.
// thread t: jg = t&31 owns j = jg*8 .. jg*8+7 ; kg = t>>5 owns k = kg*16 .. kg*16+15
__global__ __launch_bounds__(512, 2) void rnn_fused(
    const float* __restrict__ xin,   // [T,B,I]
    const float* __restrict__ Wih,   // [H,I]
    const float* __restrict__ Whh,   // [H,H]
    const float* __restrict__ Who,   // [O,H]
    float* __restrict__ out)         // [T*B*O] outputs ++ [B*H] h_last
{
  const int b   = blockIdx.x;
  const int tid = threadIdx.x;
  const int jg  = tid & 31;
  const int kg  = tid >> 5;

  __shared__ __align__(16) float h_s[H];
  __shared__ __align__(16) float x_s[2][I];
  __shared__ __align__(16) float red[16 * RED_S];
  __shared__ __align__(16) float red2[16 * RED2_S];

  // ---- stage weights into registers (resident for all 4096 steps) ----
  float whh[8][16];
#pragma unroll
  for (int jj = 0; jj < 8; ++jj) {
    const float* r = Whh + (size_t)(jg * 8 + jj) * H + kg * 16;
#pragma unroll
    for (int q = 0; q < 4; ++q) {
      float4 v = *reinterpret_cast<const float4*>(r + q * 4);
      whh[jj][q * 4 + 0] = v.x;
      whh[jj][q * 4 + 1] = v.y;
      whh[jj][q * 4 + 2] = v.z;
      whh[jj][q * 4 + 3] = v.w;
    }
  }
  float wih[8][4];
#pragma unroll
  for (int jj = 0; jj < 8; ++jj) {
    float4 v = *reinterpret_cast<const float4*>(Wih + (size_t)(jg * 8 + jj) * I + kg * 4);
    wih[jj][0] = v.x;
    wih[jj][1] = v.y;
    wih[jj][2] = v.z;
    wih[jj][3] = v.w;
  }
  float who[2][16];
#pragma unroll
  for (int oo = 0; oo < 2; ++oo) {
    const float* r = Who + (size_t)(jg * 2 + oo) * H + kg * 16;
#pragma unroll
    for (int q = 0; q < 4; ++q) {
      float4 v = *reinterpret_cast<const float4*>(r + q * 4);
      who[oo][q * 4 + 0] = v.x;
      who[oo][q * 4 + 1] = v.y;
      who[oo][q * 4 + 2] = v.z;
      who[oo][q * 4 + 3] = v.w;
    }
  }

  // ---- init: h0 = 0, preload x for t=0 ----
  if (tid < H) h_s[tid] = 0.f;
  if (tid < 16) {
    float4 v = *reinterpret_cast<const float4*>(xin + (size_t)b * I + tid * 4);
    *reinterpret_cast<float4*>(&x_s[0][tid * 4]) = v;
  }

  for (int t = 0; t < T; ++t) {
    __syncthreads();  // B1: h_s(t-1), x_s[t&1], red2(t-1) all ready

    // deferred y-store for step t-1 (overlaps with stage 1 compute)
    if (t > 0 && tid < O) {
      float y = 0.f;
#pragma unroll
      for (int g = 0; g < 16; ++g) y += red2[g * RED2_S + tid];
      out[((size_t)(t - 1) * B + b) * O + tid] = y;
    }

    // prefetch x for t+1 into the alternate LDS buffer
    float4 xpre;
    const bool pre = (t + 1 < T) && (tid < 16);
    if (pre)
      xpre = *reinterpret_cast<const float4*>(xin + ((size_t)(t + 1) * B + b) * I + tid * 4);

    // ---- stage 1: hh + ih partial dot products ----
    const float* hp = h_s + kg * 16;
    float hf[16];
#pragma unroll
    for (int q = 0; q < 4; ++q) {
      float4 v = *reinterpret_cast<const float4*>(hp + q * 4);
      hf[q * 4 + 0] = v.x;
      hf[q * 4 + 1] = v.y;
      hf[q * 4 + 2] = v.z;
      hf[q * 4 + 3] = v.w;
    }
    float4 xv = *reinterpret_cast<const float4*>(&x_s[t & 1][kg * 4]);
    float p[8];
#pragma unroll
    for (int jj = 0; jj < 8; ++jj) {
      float a = 0.f;
#pragma unroll
      for (int ki = 0; ki < 16; ++ki) a = fmaf(hf[ki], whh[jj][ki], a);
      a = fmaf(xv.x, wih[jj][0], a);
      a = fmaf(xv.y, wih[jj][1], a);
      a = fmaf(xv.z, wih[jj][2], a);
      a = fmaf(xv.w, wih[jj][3], a);
      p[jj] = a;
    }
    float* rp = red + kg * RED_S + jg * 8;
    *reinterpret_cast<float4*>(rp)     = make_float4(p[0], p[1], p[2], p[3]);
    *reinterpret_cast<float4*>(rp + 4) = make_float4(p[4], p[5], p[6], p[7]);

    if (pre) *reinterpret_cast<float4*>(&x_s[(t + 1) & 1][tid * 4]) = xpre;

    __syncthreads();  // B2: red ready

    // ---- stage 2: reduce 16 partials, add-activation -> h_s ----
    if (tid < H) {
      float v = 0.f;
#pragma unroll
      for (int g = 0; g < 16; ++g) v += red[g * RED_S + tid];
      v = fminf(fmaxf(v, -15.f), 15.f);
      float e = __expf(2.f * v);          // tanh(v) = 1 - 2/(e^{2v}+1)
      h_s[tid] = 1.f - 2.f / (e + 1.f);
    }
    __syncthreads();  // B3: h_s(t) ready

    // ---- stage 3: out-projection partials ----
    float hg[16];
#pragma unroll
    for (int q = 0; q < 4; ++q) {
      float4 v = *reinterpret_cast<const float4*>(h_s + kg * 16 + q * 4);
      hg[q * 4 + 0] = v.x;
      hg[q * 4 + 1] = v.y;
      hg[q * 4 + 2] = v.z;
      hg[q * 4 + 3] = v.w;
    }
    float q0 = 0.f, q1 = 0.f;
#pragma unroll
    for (int ki = 0; ki < 16; ++ki) {
      q0 = fmaf(hg[ki], who[0][ki], q0);
      q1 = fmaf(hg[ki], who[1][ki], q1);
    }
    *reinterpret_cast<float2*>(&red2[kg * RED2_S + jg * 2]) = make_float2(q0, q1);
  }

  __syncthreads();
  // final y-store for t = T-1
  if (tid < O) {
    float y = 0.f;
#pragma unroll
    for (int g = 0; g < 16; ++g) y += red2[g * RED2_S + tid];
    out[((size_t)(T - 1) * B + b) * O + tid] = y;
  }
  // h_last
  if (tid < H) out[(size_t)T * B * O + (size_t)b * H + tid] = h_s[tid];
}

}  // namespace

extern "C" void kernel_launch(void* const* d_in, const int* in_sizes, int n_in,
                              void* d_out, int out_size, void* d_ws, size_t ws_size,
                              hipStream_t stream) {
  const float* xin = (const float*)d_in[0];
  const float* Wih = (const float*)d_in[1];
  const float* Whh = (const float*)d_in[2];
  const float* Who = (const float*)d_in[3];
  float* out = (float*)d_out;
  hipLaunchKernelGGL(rnn_fused, dim3(B), dim3(512), 0, stream,
                     xin, Wih, Whh, Who, out);
}